// Round 5
// baseline (160.779 us; speedup 1.0000x reference)
//
#include <hip/hip_runtime.h>

// Problem constants (match reference):
// N=100000, K=20, D=96, H=1024, C=7, RIDGE=100
#define D_DIM 96
#define K_NN  20
#define H_DIM 1024
#define C_CLS 7

// ---------------------------------------------------------------------------
// ws layout (bytes):
//   4096    flags     [0]=masked_count [1]=idx_is64 [2]=done_tickets [3]=ridge_done
//   4160    wo_flag   1 f32
//   8192    preds     N int32              (400000 B)
//   408192  list      N int32              (400000 B)
//   836864  wo        1024*7 f32           (28672 B)
//   865536  Gn        1024*1024 f32        (4194304 B; only touched if M>0)
//   total need: 5059840 B
// ---------------------------------------------------------------------------

// K1: proto staging+normalization (float4, LDS), flags init + index-dtype
// detection (block 0), prototype-logit argmax. 1 point/thread, 391 blocks.
__global__ void k_preds(const float* __restrict__ feat,
                        const float* __restrict__ proto,
                        const long long* __restrict__ idx_ll,
                        int* __restrict__ preds, int* __restrict__ flags, int N) {
  __shared__ float4 pn4[C_CLS * (D_DIM / 4)];  // 168 float4
  __shared__ float inv[C_CLS];
  __shared__ int any_big;
  const int t = threadIdx.x;
  if (t == 0) any_big = 0;
  if (t < C_CLS * (D_DIM / 4)) pn4[t] = ((const float4*)proto)[t];
  if (blockIdx.x == 0) {
    // dtype detection: sample first 1024 slots interpreted as int64.
    // int32 data read as int64 pairs two indices -> value >= 2^32 (or <0)
    // unless the paired high word is 0 (prob ~1e-5 per slot, 1024 samples).
    for (int j = t; j < 1024; j += blockDim.x) {
      long long v = idx_ll[j];
      if (v < 0 || v >= N) any_big = 1;  // benign race, all write 1
    }
  }
  __syncthreads();
  if (t < C_CLS) {
    const float* row = (const float*)&pn4[t * (D_DIM / 4)];
    float ss = 0.f;
    for (int d = 0; d < D_DIM; d++) ss += row[d] * row[d];
    inv[t] = 1.0f / fmaxf(sqrtf(ss), 1e-12f);
  }
  __syncthreads();
  if (t < C_CLS * (D_DIM / 4)) {
    float s = inv[t / (D_DIM / 4)];
    float4 v = pn4[t];
    v.x *= s; v.y *= s; v.z *= s; v.w *= s;
    pn4[t] = v;
  }
  if (blockIdx.x == 0 && t == 0) {
    flags[0] = 0;                 // masked count
    flags[1] = any_big ? 0 : 1;   // is64
    flags[2] = 0;                 // completion tickets (k_fused)
    flags[3] = 0;                 // ridge_done flag (k_fused)
  }
  __syncthreads();

  int i = blockIdx.x * blockDim.x + t;
  int j = min(i, N - 1);  // branchless tail (dup of last row)
  const float4* fp = (const float4*)feat + (size_t)j * (D_DIM / 4);
  float s[C_CLS];
#pragma unroll
  for (int c = 0; c < C_CLS; c++) s[c] = 0.f;
#pragma unroll 4
  for (int q = 0; q < D_DIM / 4; q++) {
    float4 a = fp[q];
#pragma unroll
    for (int c = 0; c < C_CLS; c++) {
      float4 p = pn4[c * (D_DIM / 4) + q];  // wave-uniform LDS broadcast, b128
      s[c] += a.x * p.x + a.y * p.y + a.z * p.z + a.w * p.w;
    }
  }
  float best = s[0]; int bi = 0;
#pragma unroll
  for (int c = 1; c < C_CLS; c++)  // strict >, first-max: matches jnp.argmax
    if (s[c] > best) { best = s[c]; bi = c; }
  if (i < N) preds[i] = bi;
}

__device__ inline void reduce7_512(const float* val, volatile float* out,
                                   float* red) {
  int lane = threadIdx.x & 63, wave = threadIdx.x >> 6;  // 8 waves
#pragma unroll
  for (int c = 0; c < C_CLS; c++) {
    float v = val[c];
#pragma unroll
    for (int o = 32; o > 0; o >>= 1) v += __shfl_down(v, o, 64);
    if (lane == 0) red[wave * C_CLS + c] = v;
  }
  __syncthreads();
  if (threadIdx.x == 0) {
#pragma unroll
    for (int c = 0; c < C_CLS; c++) {
      float s = 0.f;
      for (int wv = 0; wv < 8; wv++) s += red[wv * C_CLS + c];
      out[c] = s;
    }
  }
  __syncthreads();
}

// K2: fused mask -> (last block) ridge -> output.
//   Phase 1 (all 256 blocks, 512 thr): KNN-consistency + prior mask, list append.
//   Arrival: device-scope ACQ_REL ticket; the LAST block has acquired all
//     other blocks' list/pred writes (their fetch_add releases them).
//   Phase 2 (last block only): b = Q + one-hot-weighted relu-projections;
//     Gn = G + F^T F if M>0 (else A = G, zero copies); block-CG on A+100I.
//     A = 100I + rank-M PSD -> CG exact in <= M+1 iters; b=0 -> exits at it 0.
//     Then RELEASE-store ridge_done; other blocks ACQUIRE-spin (s_sleep poll).
//   Phase 3 (all blocks): out = feat_h @ wo, or exact zero-fill if ||wo||=0.
// Co-residency for the spin is unconditional: 256 blocks, 1 block/CU always
// fits (512 thr, <=2 waves/SIMD via launch_bounds, 29 KB LDS).
__global__ void __launch_bounds__(512, 2)
k_fused(const float* __restrict__ feat, const float* __restrict__ w,
        const float* __restrict__ Q, const float* __restrict__ G,
        const int* __restrict__ preds, const void* __restrict__ nearv,
        const float* __restrict__ coords, const float* __restrict__ normz,
        int* __restrict__ flags, int* __restrict__ list,
        float* __restrict__ Gn, float* __restrict__ wo,
        float* __restrict__ wo_flag, float* __restrict__ out, int N) {
  __shared__ float psh[H_DIM * C_CLS];   // 28 KB (ridge staging / CG p)
  __shared__ float red[8 * C_CLS];
  __shared__ float rs[C_CLS], bn2[C_CLS], pap[C_CLS], rsn[C_CLS];
  __shared__ int s_last;
  const int t = threadIdx.x;

  // ---------------- phase 1: mask ----------------
  {
    int i = blockIdx.x * 512 + t;
    if (i < N) {
      int p = preds[i];
      int idx[K_NN];
      if (flags[1]) {
        const longlong2* nn = (const longlong2*)((const long long*)nearv + (long long)i * K_NN);
#pragma unroll
        for (int k = 0; k < K_NN / 2; k++) {
          longlong2 v = nn[k];
          idx[2 * k] = (int)v.x; idx[2 * k + 1] = (int)v.y;
        }
      } else {
        const int4* nn = (const int4*)((const int*)nearv + (size_t)i * K_NN);
#pragma unroll
        for (int k = 0; k < K_NN / 4; k++) {
          int4 v = nn[k];
          idx[4 * k] = v.x; idx[4 * k + 1] = v.y; idx[4 * k + 2] = v.z; idx[4 * k + 3] = v.w;
        }
      }
      int cnt = 0;
#pragma unroll
      for (int k = 0; k < K_NN; k++) cnt += (preds[idx[k]] == p) ? 1 : 0;
      bool cmask = (cnt >= 17);  // cnt/20 > 0.8  <=>  cnt >= 17 (exact in f32)
      bool plane = (p == 2) || (p == 3) || (p == 4);
      bool man   = (p == 5);
      bool other = (p == 0) || (p == 1) || (p == 6);
      float nz = normz[i];
      bool ground = plane && (nz > 0.9f) && (coords[(size_t)i * 3 + 2] < -10.0f);
      bool g = ground || other || man;
      bool m = (man && (nz < 0.1f)) || other || plane;
      if (cmask && g && m) {
        int pos = atomicAdd(&flags[0], 1);  // device scope
        list[pos] = i;
      }
    }
  }
  __syncthreads();
  if (t == 0) {
    int tick = __hip_atomic_fetch_add(&flags[2], 1, __ATOMIC_ACQ_REL,
                                      __HIP_MEMORY_SCOPE_AGENT);
    s_last = (tick == (int)gridDim.x - 1) ? 1 : 0;
  }
  __syncthreads();

  // ---------------- phase 2: ridge (last block) ----------------
  if (s_last) {
    const int M = flags[0];
    float b[2][C_CLS];
#pragma unroll
    for (int j = 0; j < 2; j++) {
      int h = t + 512 * j;
#pragma unroll
      for (int c = 0; c < C_CLS; c++) b[j][c] = Q[h * C_CLS + c];
    }
    const float* Amat = G;  // M==0: solve on input Gram directly (no copy)
    if (M > 0) {
      for (int m = 0; m < M; m++) {
        int im = list[m];
        float sv[2];
#pragma unroll
        for (int j = 0; j < 2; j++) {
          int h = t + 512 * j;
          float s = 0.f;
          for (int d = 0; d < D_DIM; d++)
            s += feat[(size_t)im * D_DIM + d] * w[(size_t)d * H_DIM + h];
          s = fmaxf(s, 0.f);
          sv[j] = s;
          b[j][preds[im]] += s;
          psh[h] = s;
        }
        __syncthreads();
#pragma unroll
        for (int j = 0; j < 2; j++) {
          int h = t + 512 * j;
          float sh = sv[j];
          float* grow = Gn + (size_t)h * H_DIM;
          const float* g0 = G + (size_t)h * H_DIM;
          if (m == 0) { for (int k = 0; k < H_DIM; k++) grow[k] = g0[k] + sh * psh[k]; }
          else        { for (int k = 0; k < H_DIM; k++) grow[k] += sh * psh[k]; }
        }
        __syncthreads();
      }
      Amat = Gn;
    }

    float x[2][C_CLS], r[2][C_CLS], p[2][C_CLS], t7[C_CLS];
#pragma unroll
    for (int c = 0; c < C_CLS; c++) t7[c] = 0.f;
#pragma unroll
    for (int j = 0; j < 2; j++)
#pragma unroll
      for (int c = 0; c < C_CLS; c++) {
        x[j][c] = 0.f; r[j][c] = b[j][c]; p[j][c] = b[j][c];
        t7[c] += b[j][c] * b[j][c];
      }
    reduce7_512(t7, rs, red);
    if (t == 0) {
#pragma unroll
      for (int c = 0; c < C_CLS; c++) bn2[c] = rs[c];
    }
    __syncthreads();

    for (int it = 0; it < H_DIM; it++) {
      bool done = true;
#pragma unroll
      for (int c = 0; c < C_CLS; c++)
        done = done && (rs[c] <= bn2[c] * 1e-16f + 1e-30f);
      if (done) break;  // uniform: rs/bn2 live in LDS

#pragma unroll
      for (int j = 0; j < 2; j++)
#pragma unroll
        for (int c = 0; c < C_CLS; c++) psh[(t + 512 * j) * C_CLS + c] = p[j][c];
      __syncthreads();

      float ap[2][C_CLS];
#pragma unroll
      for (int j = 0; j < 2; j++) {
#pragma unroll
        for (int c = 0; c < C_CLS; c++) ap[j][c] = 100.0f * p[j][c];
        const float* grow = Amat + (size_t)(t + 512 * j) * H_DIM;
        for (int k = 0; k < H_DIM; k++) {
          float g = grow[k];
#pragma unroll
          for (int c = 0; c < C_CLS; c++) ap[j][c] += g * psh[k * C_CLS + c];
        }
      }
#pragma unroll
      for (int c = 0; c < C_CLS; c++)
        t7[c] = p[0][c] * ap[0][c] + p[1][c] * ap[1][c];
      reduce7_512(t7, pap, red);

      float a[C_CLS], rsold[C_CLS];
#pragma unroll
      for (int c = 0; c < C_CLS; c++) {
        rsold[c] = rs[c];
        bool act = rs[c] > bn2[c] * 1e-16f + 1e-30f;
        a[c] = act ? rsold[c] / fmaxf(pap[c], 1e-37f) : 0.f;
        t7[c] = 0.f;
      }
#pragma unroll
      for (int j = 0; j < 2; j++)
#pragma unroll
        for (int c = 0; c < C_CLS; c++) {
          x[j][c] += a[c] * p[j][c];
          r[j][c] -= a[c] * ap[j][c];
          t7[c] += r[j][c] * r[j][c];
        }
      reduce7_512(t7, rsn, red);
#pragma unroll
      for (int c = 0; c < C_CLS; c++) {
        float bb = rsn[c] / fmaxf(rsold[c], 1e-37f);
#pragma unroll
        for (int j = 0; j < 2; j++) p[j][c] = r[j][c] + bb * p[j][c];
      }
      if (t == 0) {
#pragma unroll
        for (int c = 0; c < C_CLS; c++) rs[c] = rsn[c];
      }
      __syncthreads();
    }

#pragma unroll
    for (int c = 0; c < C_CLS; c++) t7[c] = 0.f;
#pragma unroll
    for (int j = 0; j < 2; j++) {
      int h = t + 512 * j;
#pragma unroll
      for (int c = 0; c < C_CLS; c++) {
        wo[h * C_CLS + c] = x[j][c];
        t7[0] += fabsf(x[j][c]);
      }
    }
#pragma unroll
    for (int c = 1; c < C_CLS; c++) t7[c] = 0.f;
    reduce7_512(t7, rsn, red);
    if (t == 0) *wo_flag = rsn[0];
    __syncthreads();
    if (t == 0)
      __hip_atomic_store(&flags[3], 1, __ATOMIC_RELEASE, __HIP_MEMORY_SCOPE_AGENT);
  } else {
    if (t == 0) {
      while (__hip_atomic_load(&flags[3], __ATOMIC_ACQUIRE,
                               __HIP_MEMORY_SCOPE_AGENT) == 0)
        __builtin_amdgcn_s_sleep(8);
    }
    __syncthreads();
  }

  // ---------------- phase 3: output ----------------
  if (*wo_flag == 0.0f) {
    // exact: feat_h @ 0 = 0. Grid-stride float4 fill of N*C = 175000 float4.
    int total4 = (N * C_CLS) / 4;
    int stride = gridDim.x * blockDim.x;
    float4 z = make_float4(0.f, 0.f, 0.f, 0.f);
    for (int v = blockIdx.x * 512 + t; v < total4; v += stride)
      ((float4*)out)[v] = z;
    return;
  }
  int i = blockIdx.x * 512 + t;
  if (i >= N) return;
  float f[D_DIM];
  const float4* fp = (const float4*)(feat + (size_t)i * D_DIM);
#pragma unroll
  for (int q = 0; q < D_DIM / 4; q++) {
    float4 v = fp[q];
    f[4 * q] = v.x; f[4 * q + 1] = v.y; f[4 * q + 2] = v.z; f[4 * q + 3] = v.w;
  }
  float acc[C_CLS];
#pragma unroll
  for (int c = 0; c < C_CLS; c++) acc[c] = 0.f;
  for (int hh = 0; hh < H_DIM; hh++) {
    float s = 0.f;
#pragma unroll 8
    for (int d = 0; d < D_DIM; d++) s += f[d] * w[(size_t)d * H_DIM + hh];
    s = fmaxf(s, 0.f);
    const float* wrow = wo + hh * C_CLS;
#pragma unroll
    for (int c = 0; c < C_CLS; c++) acc[c] += s * wrow[c];
  }
#pragma unroll
  for (int c = 0; c < C_CLS; c++) out[(size_t)i * C_CLS + c] = acc[c];
}

extern "C" void kernel_launch(void* const* d_in, const int* in_sizes, int n_in,
                              void* d_out, int out_size, void* d_ws, size_t ws_size,
                              hipStream_t stream) {
  const float* feat   = (const float*)d_in[0];
  const float* proto  = (const float*)d_in[1];
  const float* w      = (const float*)d_in[2];
  const float* Q      = (const float*)d_in[3];
  const float* G      = (const float*)d_in[4];
  const float* coords = (const float*)d_in[5];
  const float* normz  = (const float*)d_in[6];
  const void*  nearv  = d_in[7];
  float* out = (float*)d_out;

  const int N = in_sizes[0] / D_DIM;  // 100000

  char* WS = (char*)d_ws;
  int*   flags   = (int*)(WS + 4096);
  float* wo_flag = (float*)(WS + 4160);
  int*   preds   = (int*)(WS + 8192);
  int*   list    = (int*)(WS + 8192 + 400000);
  float* wo      = (float*)(WS + 836864);
  float* Gn      = (float*)(WS + 865536);
  // total ws need: 5059840 bytes
  if (ws_size < 5059840) return;  // constant per session; visible failure if hit

  int nblk = (N + 255) / 256;  // 391 blocks
  hipLaunchKernelGGL(k_preds, dim3(nblk), dim3(256), 0, stream,
                     feat, proto, (const long long*)nearv, preds, flags, N);
  // 256 blocks x 512 threads: covers N (131072 >= 100000), 1 block/CU always
  // co-resident -> last-block/spin pattern is deadlock-free.
  hipLaunchKernelGGL(k_fused, dim3(256), dim3(512), 0, stream,
                     feat, w, Q, G, preds, nearv, coords, normz,
                     flags, list, Gn, wo, wo_flag, out, N);
}

// Round 6
// 119.101 us; speedup vs baseline: 1.3499x; 1.3499x over previous
//
#include <hip/hip_runtime.h>

// Problem constants (match reference):
// N=100000, K=20, D=96, H=1024, C=7, RIDGE=100
#define D_DIM 96
#define K_NN  20
#define H_DIM 1024
#define C_CLS 7

// ---------------------------------------------------------------------------
// ws layout (bytes):
//   4096    flags     [0]=masked_count [1]=idx_is64
//   4160    wo_flag   1 f32
//   8192    preds     N uint8              (100000 B)
//   408192  list      N int32              (400000 B)
//   836864  wo        1024*7 f32           (28672 B)
//   865536  Gn        1024*1024 f32        (4194304 B; only touched if M>0)
//   total need: 5059840 B
//
// NOTE (round-5 lesson): do NOT fuse across the global dependencies with
// device-scope tickets/spins — agent-scope acq/rel from 256 blocks costs
// ~60 us in cross-XCD cache maintenance on MI355X. Kernel boundaries
// (~2 us each) are the cheap global-visibility mechanism.
// ---------------------------------------------------------------------------

// K1: proto staging+normalization (float4, LDS), flags init + index-dtype
// detection (block 0), prototype-logit argmax. 1 point/thread, 391 blocks
// (1.5 blocks/CU -> all CUs pulling HBM).
__global__ void k_preds(const float* __restrict__ feat,
                        const float* __restrict__ proto,
                        const long long* __restrict__ idx_ll,
                        unsigned char* __restrict__ preds,
                        int* __restrict__ flags, int N) {
  __shared__ float4 pn4[C_CLS * (D_DIM / 4)];  // 168 float4
  __shared__ float inv[C_CLS];
  __shared__ int any_big;
  const int t = threadIdx.x;
  if (t == 0) any_big = 0;
  if (t < C_CLS * (D_DIM / 4)) pn4[t] = ((const float4*)proto)[t];
  if (blockIdx.x == 0) {
    // dtype detection: sample first 1024 slots interpreted as int64.
    // int32 data read as int64 pairs two indices -> value >= 2^32 (or <0)
    // unless the paired high word is 0 (prob ~1e-5 per slot, 1024 samples).
    for (int j = t; j < 1024; j += blockDim.x) {
      long long v = idx_ll[j];
      if (v < 0 || v >= N) any_big = 1;  // benign race, all write 1
    }
  }
  __syncthreads();
  if (t < C_CLS) {
    const float* row = (const float*)&pn4[t * (D_DIM / 4)];
    float ss = 0.f;
    for (int d = 0; d < D_DIM; d++) ss += row[d] * row[d];
    inv[t] = 1.0f / fmaxf(sqrtf(ss), 1e-12f);
  }
  __syncthreads();
  if (t < C_CLS * (D_DIM / 4)) {
    float s = inv[t / (D_DIM / 4)];
    float4 v = pn4[t];
    v.x *= s; v.y *= s; v.z *= s; v.w *= s;
    pn4[t] = v;
  }
  if (blockIdx.x == 0 && t == 0) {
    flags[0] = 0;                 // masked count
    flags[1] = any_big ? 0 : 1;   // is64
  }
  __syncthreads();

  int i = blockIdx.x * blockDim.x + t;
  int j = min(i, N - 1);  // branchless tail (dup of last row)
  const float4* fp = (const float4*)feat + (size_t)j * (D_DIM / 4);
  float s[C_CLS];
#pragma unroll
  for (int c = 0; c < C_CLS; c++) s[c] = 0.f;
#pragma unroll 4
  for (int q = 0; q < D_DIM / 4; q++) {
    float4 a = fp[q];
#pragma unroll
    for (int c = 0; c < C_CLS; c++) {
      float4 p = pn4[c * (D_DIM / 4) + q];  // wave-uniform LDS broadcast, b128
      s[c] += a.x * p.x + a.y * p.y + a.z * p.z + a.w * p.w;
    }
  }
  float best = s[0]; int bi = 0;
#pragma unroll
  for (int c = 1; c < C_CLS; c++)  // strict >, first-max: matches jnp.argmax
    if (s[c] > best) { best = s[c]; bi = c; }
  if (i < N) preds[i] = (unsigned char)bi;
}

// K2: KNN-consistency + prior-filter mask + list compaction. preds are u8
// (100 KB working set -> ~4x better cache-line utilization for the 2M
// random gathers than i32).
__global__ void k_mask(const unsigned char* __restrict__ preds,
                       const void* __restrict__ nearv,
                       const float* __restrict__ coords, const float* __restrict__ normz,
                       int* __restrict__ flags, int* __restrict__ list, int N) {
  int i = blockIdx.x * blockDim.x + threadIdx.x;
  if (i >= N) return;
  int p = preds[i];
  int idx[K_NN];
  if (flags[1]) {
    const longlong2* nn = (const longlong2*)((const long long*)nearv + (long long)i * K_NN);
#pragma unroll
    for (int k = 0; k < K_NN / 2; k++) {
      longlong2 v = nn[k];
      idx[2 * k] = (int)v.x; idx[2 * k + 1] = (int)v.y;
    }
  } else {
    const int4* nn = (const int4*)((const int*)nearv + (size_t)i * K_NN);
#pragma unroll
    for (int k = 0; k < K_NN / 4; k++) {
      int4 v = nn[k];
      idx[4 * k] = v.x; idx[4 * k + 1] = v.y; idx[4 * k + 2] = v.z; idx[4 * k + 3] = v.w;
    }
  }
  int cnt = 0;
#pragma unroll
  for (int k = 0; k < K_NN; k++) cnt += (preds[idx[k]] == p) ? 1 : 0;
  bool cmask = (cnt >= 17);  // cnt/20 > 0.8  <=>  cnt >= 17 (exact in f32)
  bool plane = (p == 2) || (p == 3) || (p == 4);
  bool man   = (p == 5);
  bool other = (p == 0) || (p == 1) || (p == 6);
  float nz = normz[i];
  bool ground = plane && (nz > 0.9f) && (coords[(size_t)i * 3 + 2] < -10.0f);
  bool g = ground || other || man;
  bool m = (man && (nz < 0.1f)) || other || plane;
  if (cmask && g && m) {
    int pos = atomicAdd(&flags[0], 1);
    list[pos] = i;
  }
}

__device__ inline void block_reduce7(const float* val, volatile float* out,
                                     float* red) {
  int lane = threadIdx.x & 63, wave = threadIdx.x >> 6;
#pragma unroll
  for (int c = 0; c < C_CLS; c++) {
    float v = val[c];
#pragma unroll
    for (int o = 32; o > 0; o >>= 1) v += __shfl_down(v, o, 64);
    if (lane == 0) red[wave * C_CLS + c] = v;
  }
  __syncthreads();
  if (threadIdx.x == 0) {
#pragma unroll
    for (int c = 0; c < C_CLS; c++) {
      float s = 0.f;
      for (int wv = 0; wv < 16; wv++) s += red[wv * C_CLS + c];
      out[c] = s;
    }
  }
  __syncthreads();
}

// K3: single block, 1024 threads. Computes b = Qn row in registers (loop over
// masked list). If M>0, builds Gn = G + F^T F in ws (fused, no pre-copy) and
// solves on Gn; if M==0, solves directly on A = G + 100I with ZERO copies.
// Block-CG: A = 100I + PSD, converges in <= M+1 iters exactly; with b=0 the
// done-check exits at iteration 0 -- no row of A is ever read.
__global__ void __launch_bounds__(1024) k_ridge(const float* __restrict__ feat,
                                                const float* __restrict__ w,
                                                const float* __restrict__ Q,
                                                const float* __restrict__ G,
                                                const unsigned char* __restrict__ preds,
                                                const int* __restrict__ flags,
                                                const int* __restrict__ list,
                                                float* __restrict__ Gn,
                                                float* __restrict__ wo,
                                                float* __restrict__ wo_flag) {
  const int h = threadIdx.x;
  __shared__ float psh[H_DIM * C_CLS];   // 28 KB (reused: f-staging then CG p)
  __shared__ float red[16 * C_CLS];
  __shared__ float rs[C_CLS], bn2[C_CLS], pap[C_CLS], rsn[C_CLS];

  const int M = flags[0];
  float b[C_CLS];
#pragma unroll
  for (int c = 0; c < C_CLS; c++) b[c] = Q[h * C_CLS + c];
  const float* Amat = G;  // M==0: read input Gram directly (no copy)
  if (M > 0) {
    for (int m = 0; m < M; m++) {
      int i = list[m];
      float s = 0.f;
      for (int d = 0; d < D_DIM; d++)
        s += feat[(size_t)i * D_DIM + d] * w[(size_t)d * H_DIM + h];
      s = fmaxf(s, 0.f);
      b[preds[i]] += s;
      psh[h] = s;
      __syncthreads();
      float sh = psh[h];
      if (m == 0) {
        for (int k = 0; k < H_DIM; k++)
          Gn[(size_t)h * H_DIM + k] = G[(size_t)h * H_DIM + k] + sh * psh[k];
      } else {
        for (int k = 0; k < H_DIM; k++)
          Gn[(size_t)h * H_DIM + k] += sh * psh[k];
      }
      __syncthreads();
    }
    Amat = Gn;
  }

  float x[C_CLS], r[C_CLS], p[C_CLS], t7[C_CLS];
#pragma unroll
  for (int c = 0; c < C_CLS; c++) {
    x[c] = 0.f; r[c] = b[c]; p[c] = b[c];
    t7[c] = b[c] * b[c];
  }
  block_reduce7(t7, rs, red);
  if (h == 0) {
#pragma unroll
    for (int c = 0; c < C_CLS; c++) bn2[c] = rs[c];
  }
  __syncthreads();

  for (int it = 0; it < H_DIM; it++) {
    bool done = true;
#pragma unroll
    for (int c = 0; c < C_CLS; c++)
      done = done && (rs[c] <= bn2[c] * 1e-16f + 1e-30f);
    if (done) break;  // uniform: rs/bn2 live in LDS

#pragma unroll
    for (int c = 0; c < C_CLS; c++) psh[h * C_CLS + c] = p[c];
    __syncthreads();

    float ap[C_CLS];
#pragma unroll
    for (int c = 0; c < C_CLS; c++) ap[c] = 100.0f * p[c];
    const float* grow = Amat + (size_t)h * H_DIM;
    for (int k = 0; k < H_DIM; k++) {
      float g = grow[k];
#pragma unroll
      for (int c = 0; c < C_CLS; c++) ap[c] += g * psh[k * C_CLS + c];
    }
#pragma unroll
    for (int c = 0; c < C_CLS; c++) t7[c] = p[c] * ap[c];
    block_reduce7(t7, pap, red);

    float a[C_CLS], rsold[C_CLS];
#pragma unroll
    for (int c = 0; c < C_CLS; c++) {
      rsold[c] = rs[c];
      bool act = rs[c] > bn2[c] * 1e-16f + 1e-30f;
      a[c] = act ? rsold[c] / fmaxf(pap[c], 1e-37f) : 0.f;
    }
#pragma unroll
    for (int c = 0; c < C_CLS; c++) {
      x[c] += a[c] * p[c];
      r[c] -= a[c] * ap[c];
      t7[c] = r[c] * r[c];
    }
    block_reduce7(t7, rsn, red);
#pragma unroll
    for (int c = 0; c < C_CLS; c++) {
      float bb = rsn[c] / fmaxf(rsold[c], 1e-37f);
      p[c] = r[c] + bb * p[c];
    }
    if (h == 0) {
#pragma unroll
      for (int c = 0; c < C_CLS; c++) rs[c] = rsn[c];
    }
    __syncthreads();
  }

#pragma unroll
  for (int c = 0; c < C_CLS; c++) wo[h * C_CLS + c] = x[c];
  float s = 0.f;
#pragma unroll
  for (int c = 0; c < C_CLS; c++) s += fabsf(x[c]);
  t7[0] = s;
#pragma unroll
  for (int c = 1; c < C_CLS; c++) t7[c] = 0.f;
  block_reduce7(t7, rsn, red);
  if (h == 0) *wo_flag = rsn[0];
}

// K4: out[i][c] = sum_h relu(feat_i . W[:,h]) * wo[h][c]. If wo == 0 (the
// data-driven common case here), this is exactly a grid-stride float4 zero
// fill (N*C = 700000 floats = 175000 float4s).
__global__ void k_out(const float* __restrict__ feat, const float* __restrict__ w,
                      const float* __restrict__ wo, const float* __restrict__ wo_flag,
                      float* __restrict__ out, int N) {
  if (*wo_flag == 0.0f) {
    int total4 = (N * C_CLS) / 4;  // 700000 % 4 == 0
    int stride = gridDim.x * blockDim.x;
    float4 z = make_float4(0.f, 0.f, 0.f, 0.f);
    for (int v = blockIdx.x * blockDim.x + threadIdx.x; v < total4; v += stride)
      ((float4*)out)[v] = z;
    return;
  }
  int i = blockIdx.x * blockDim.x + threadIdx.x;
  if (i >= N) return;
  float f[D_DIM];
  const float4* fp = (const float4*)(feat + (size_t)i * D_DIM);
#pragma unroll
  for (int q = 0; q < D_DIM / 4; q++) {
    float4 v = fp[q];
    f[4 * q] = v.x; f[4 * q + 1] = v.y; f[4 * q + 2] = v.z; f[4 * q + 3] = v.w;
  }
  float acc[C_CLS];
#pragma unroll
  for (int c = 0; c < C_CLS; c++) acc[c] = 0.f;
  for (int hh = 0; hh < H_DIM; hh++) {
    float s = 0.f;
#pragma unroll 8
    for (int d = 0; d < D_DIM; d++) s += f[d] * w[(size_t)d * H_DIM + hh];
    s = fmaxf(s, 0.f);
    const float* wrow = wo + hh * C_CLS;
#pragma unroll
    for (int c = 0; c < C_CLS; c++) acc[c] += s * wrow[c];
  }
#pragma unroll
  for (int c = 0; c < C_CLS; c++) out[(size_t)i * C_CLS + c] = acc[c];
}

extern "C" void kernel_launch(void* const* d_in, const int* in_sizes, int n_in,
                              void* d_out, int out_size, void* d_ws, size_t ws_size,
                              hipStream_t stream) {
  const float* feat   = (const float*)d_in[0];
  const float* proto  = (const float*)d_in[1];
  const float* w      = (const float*)d_in[2];
  const float* Q      = (const float*)d_in[3];
  const float* G      = (const float*)d_in[4];
  const float* coords = (const float*)d_in[5];
  const float* normz  = (const float*)d_in[6];
  const void*  nearv  = d_in[7];
  float* out = (float*)d_out;

  const int N = in_sizes[0] / D_DIM;  // 100000

  char* WS = (char*)d_ws;
  int*            flags   = (int*)(WS + 4096);
  float*          wo_flag = (float*)(WS + 4160);
  unsigned char*  preds   = (unsigned char*)(WS + 8192);
  int*            list    = (int*)(WS + 408192);
  float*          wo      = (float*)(WS + 836864);
  float*          Gn      = (float*)(WS + 865536);
  // total ws need: 5059840 bytes
  if (ws_size < 5059840) return;  // constant per session; visible failure if hit

  int nblk = (N + 255) / 256;  // 391 blocks: 1.5 blocks/CU, all CUs active
  hipLaunchKernelGGL(k_preds, dim3(nblk), dim3(256), 0, stream,
                     feat, proto, (const long long*)nearv, preds, flags, N);
  hipLaunchKernelGGL(k_mask, dim3(nblk), dim3(256), 0, stream,
                     preds, nearv, coords, normz, flags, list, N);
  hipLaunchKernelGGL(k_ridge, dim3(1), dim3(1024), 0, stream,
                     feat, w, Q, G, preds, flags, list, Gn, wo, wo_flag);
  int oblk = ((N * C_CLS) / 4 + 255) / 256;  // 684 blocks for the fill path
  hipLaunchKernelGGL(k_out, dim3(oblk), dim3(256), 0, stream,
                     feat, w, wo, wo_flag, out, N);
}

// Round 7
// 118.494 us; speedup vs baseline: 1.3568x; 1.0051x over previous
//
#include <hip/hip_runtime.h>

// Problem constants (match reference):
// N=100000, K=20, D=96, H=1024, C=7, RIDGE=100
#define D_DIM 96
#define K_NN  20
#define H_DIM 1024
#define C_CLS 7

// ---------------------------------------------------------------------------
// ws layout (bytes):
//   4096    flags     [0]=masked_count [1]=idx_is64
//   4160    wo_flag   1 f32
//   8192    preds     N uint8              (100000 B)
//   408192  list      N int32              (400000 B)
//   836864  wo        1024*7 f32           (28672 B)
//   865536  Gn        1024*1024 f32        (4194304 B; only touched if M>0)
//   total need: 5059840 B
//
// NOTE (round-5 lesson): do NOT fuse across global dependencies with
// agent-scope tickets/spins — each acquire poll forces a per-XCD L2
// invalidate on MI355X (~60 us total from 256 blocks). Kernel boundaries
// (~2-3 us each) are the cheap global-visibility mechanism.
// ---------------------------------------------------------------------------

// K1: proto staging+normalization (float4, LDS), flags init + index-dtype
// detection (block 0), prototype-logit argmax, AND an unconditional
// grid-stride zero-fill of `out` (overlapped with feat-read latency; the
// final k_out either leaves it (wo==0 -> exact) or fully overwrites it).
__global__ void k_preds(const float* __restrict__ feat,
                        const float* __restrict__ proto,
                        const long long* __restrict__ idx_ll,
                        unsigned char* __restrict__ preds,
                        int* __restrict__ flags, float* __restrict__ out, int N) {
  __shared__ float4 pn4[C_CLS * (D_DIM / 4)];  // 168 float4
  __shared__ float inv[C_CLS];
  __shared__ int any_big;
  const int t = threadIdx.x;
  if (t == 0) any_big = 0;
  if (t < C_CLS * (D_DIM / 4)) pn4[t] = ((const float4*)proto)[t];
  if (blockIdx.x == 0) {
    // dtype detection: sample first 1024 slots interpreted as int64.
    // int32 data read as int64 pairs two indices -> value >= 2^32 (or <0)
    // unless the paired high word is 0 (prob ~1e-5 per slot, 1024 samples).
    for (int j = t; j < 1024; j += blockDim.x) {
      long long v = idx_ll[j];
      if (v < 0 || v >= N) any_big = 1;  // benign race, all write 1
    }
  }
  // unconditional zero-fill of out (N*C = 175000 float4); fire-and-forget
  // stores overlapped with the argmax's feat reads.
  {
    int total4 = (N * C_CLS) / 4;
    int stride = gridDim.x * blockDim.x;
    float4 z = make_float4(0.f, 0.f, 0.f, 0.f);
    for (int v = blockIdx.x * blockDim.x + t; v < total4; v += stride)
      ((float4*)out)[v] = z;
  }
  __syncthreads();
  if (t < C_CLS) {
    const float* row = (const float*)&pn4[t * (D_DIM / 4)];
    float ss = 0.f;
    for (int d = 0; d < D_DIM; d++) ss += row[d] * row[d];
    inv[t] = 1.0f / fmaxf(sqrtf(ss), 1e-12f);
  }
  __syncthreads();
  if (t < C_CLS * (D_DIM / 4)) {
    float s = inv[t / (D_DIM / 4)];
    float4 v = pn4[t];
    v.x *= s; v.y *= s; v.z *= s; v.w *= s;
    pn4[t] = v;
  }
  if (blockIdx.x == 0 && t == 0) {
    flags[0] = 0;                 // masked count
    flags[1] = any_big ? 0 : 1;   // is64
  }
  __syncthreads();

  int i = blockIdx.x * blockDim.x + t;
  int j = min(i, N - 1);  // branchless tail (dup of last row)
  const float4* fp = (const float4*)feat + (size_t)j * (D_DIM / 4);
  float s[C_CLS];
#pragma unroll
  for (int c = 0; c < C_CLS; c++) s[c] = 0.f;
#pragma unroll 4
  for (int q = 0; q < D_DIM / 4; q++) {
    float4 a = fp[q];
#pragma unroll
    for (int c = 0; c < C_CLS; c++) {
      float4 p = pn4[c * (D_DIM / 4) + q];  // wave-uniform LDS broadcast, b128
      s[c] += a.x * p.x + a.y * p.y + a.z * p.z + a.w * p.w;
    }
  }
  float best = s[0]; int bi = 0;
#pragma unroll
  for (int c = 1; c < C_CLS; c++)  // strict >, first-max: matches jnp.argmax
    if (s[c] > best) { best = s[c]; bi = c; }
  if (i < N) preds[i] = (unsigned char)bi;
}

// K2: KNN-consistency + prior-filter mask + list compaction. preds are u8
// (100 KB working set -> ~4x better cache-line utilization for the 2M
// random gathers than i32).
__global__ void k_mask(const unsigned char* __restrict__ preds,
                       const void* __restrict__ nearv,
                       const float* __restrict__ coords, const float* __restrict__ normz,
                       int* __restrict__ flags, int* __restrict__ list, int N) {
  int i = blockIdx.x * blockDim.x + threadIdx.x;
  if (i >= N) return;
  int p = preds[i];
  int idx[K_NN];
  if (flags[1]) {
    const longlong2* nn = (const longlong2*)((const long long*)nearv + (long long)i * K_NN);
#pragma unroll
    for (int k = 0; k < K_NN / 2; k++) {
      longlong2 v = nn[k];
      idx[2 * k] = (int)v.x; idx[2 * k + 1] = (int)v.y;
    }
  } else {
    const int4* nn = (const int4*)((const int*)nearv + (size_t)i * K_NN);
#pragma unroll
    for (int k = 0; k < K_NN / 4; k++) {
      int4 v = nn[k];
      idx[4 * k] = v.x; idx[4 * k + 1] = v.y; idx[4 * k + 2] = v.z; idx[4 * k + 3] = v.w;
    }
  }
  int cnt = 0;
#pragma unroll
  for (int k = 0; k < K_NN; k++) cnt += (preds[idx[k]] == p) ? 1 : 0;
  bool cmask = (cnt >= 17);  // cnt/20 > 0.8  <=>  cnt >= 17 (exact in f32)
  bool plane = (p == 2) || (p == 3) || (p == 4);
  bool man   = (p == 5);
  bool other = (p == 0) || (p == 1) || (p == 6);
  float nz = normz[i];
  bool ground = plane && (nz > 0.9f) && (coords[(size_t)i * 3 + 2] < -10.0f);
  bool g = ground || other || man;
  bool m = (man && (nz < 0.1f)) || other || plane;
  if (cmask && g && m) {
    int pos = atomicAdd(&flags[0], 1);
    list[pos] = i;
  }
}

__device__ inline void block_reduce7(const float* val, volatile float* out,
                                     float* red) {
  int lane = threadIdx.x & 63, wave = threadIdx.x >> 6;
#pragma unroll
  for (int c = 0; c < C_CLS; c++) {
    float v = val[c];
#pragma unroll
    for (int o = 32; o > 0; o >>= 1) v += __shfl_down(v, o, 64);
    if (lane == 0) red[wave * C_CLS + c] = v;
  }
  __syncthreads();
  if (threadIdx.x == 0) {
#pragma unroll
    for (int c = 0; c < C_CLS; c++) {
      float s = 0.f;
      for (int wv = 0; wv < 16; wv++) s += red[wv * C_CLS + c];
      out[c] = s;
    }
  }
  __syncthreads();
}

// K3: single block, 1024 threads. Computes b = Qn row in registers (loop over
// masked list). If M>0, builds Gn = G + F^T F in ws (fused, no pre-copy) and
// solves on Gn; if M==0, solves directly on A = G + 100I with ZERO copies.
// Block-CG: A = 100I + PSD, converges in <= M+1 iters exactly; with b=0 the
// done-check exits at iteration 0 -- no row of A is ever read.
__global__ void __launch_bounds__(1024) k_ridge(const float* __restrict__ feat,
                                                const float* __restrict__ w,
                                                const float* __restrict__ Q,
                                                const float* __restrict__ G,
                                                const unsigned char* __restrict__ preds,
                                                const int* __restrict__ flags,
                                                const int* __restrict__ list,
                                                float* __restrict__ Gn,
                                                float* __restrict__ wo,
                                                float* __restrict__ wo_flag) {
  const int h = threadIdx.x;
  __shared__ float psh[H_DIM * C_CLS];   // 28 KB (reused: f-staging then CG p)
  __shared__ float red[16 * C_CLS];
  __shared__ float rs[C_CLS], bn2[C_CLS], pap[C_CLS], rsn[C_CLS];

  const int M = flags[0];
  float b[C_CLS];
#pragma unroll
  for (int c = 0; c < C_CLS; c++) b[c] = Q[h * C_CLS + c];
  const float* Amat = G;  // M==0: read input Gram directly (no copy)
  if (M > 0) {
    for (int m = 0; m < M; m++) {
      int i = list[m];
      float s = 0.f;
      for (int d = 0; d < D_DIM; d++)
        s += feat[(size_t)i * D_DIM + d] * w[(size_t)d * H_DIM + h];
      s = fmaxf(s, 0.f);
      b[preds[i]] += s;
      psh[h] = s;
      __syncthreads();
      float sh = psh[h];
      if (m == 0) {
        for (int k = 0; k < H_DIM; k++)
          Gn[(size_t)h * H_DIM + k] = G[(size_t)h * H_DIM + k] + sh * psh[k];
      } else {
        for (int k = 0; k < H_DIM; k++)
          Gn[(size_t)h * H_DIM + k] += sh * psh[k];
      }
      __syncthreads();
    }
    Amat = Gn;
  }

  float x[C_CLS], r[C_CLS], p[C_CLS], t7[C_CLS];
#pragma unroll
  for (int c = 0; c < C_CLS; c++) {
    x[c] = 0.f; r[c] = b[c]; p[c] = b[c];
    t7[c] = b[c] * b[c];
  }
  block_reduce7(t7, rs, red);
  if (h == 0) {
#pragma unroll
    for (int c = 0; c < C_CLS; c++) bn2[c] = rs[c];
  }
  __syncthreads();

  for (int it = 0; it < H_DIM; it++) {
    bool done = true;
#pragma unroll
    for (int c = 0; c < C_CLS; c++)
      done = done && (rs[c] <= bn2[c] * 1e-16f + 1e-30f);
    if (done) break;  // uniform: rs/bn2 live in LDS

#pragma unroll
    for (int c = 0; c < C_CLS; c++) psh[h * C_CLS + c] = p[c];
    __syncthreads();

    float ap[C_CLS];
#pragma unroll
    for (int c = 0; c < C_CLS; c++) ap[c] = 100.0f * p[c];
    const float* grow = Amat + (size_t)h * H_DIM;
    for (int k = 0; k < H_DIM; k++) {
      float g = grow[k];
#pragma unroll
      for (int c = 0; c < C_CLS; c++) ap[c] += g * psh[k * C_CLS + c];
    }
#pragma unroll
    for (int c = 0; c < C_CLS; c++) t7[c] = p[c] * ap[c];
    block_reduce7(t7, pap, red);

    float a[C_CLS], rsold[C_CLS];
#pragma unroll
    for (int c = 0; c < C_CLS; c++) {
      rsold[c] = rs[c];
      bool act = rs[c] > bn2[c] * 1e-16f + 1e-30f;
      a[c] = act ? rsold[c] / fmaxf(pap[c], 1e-37f) : 0.f;
    }
#pragma unroll
    for (int c = 0; c < C_CLS; c++) {
      x[c] += a[c] * p[c];
      r[c] -= a[c] * ap[c];
      t7[c] = r[c] * r[c];
    }
    block_reduce7(t7, rsn, red);
#pragma unroll
    for (int c = 0; c < C_CLS; c++) {
      float bb = rsn[c] / fmaxf(rsold[c], 1e-37f);
      p[c] = r[c] + bb * p[c];
    }
    if (h == 0) {
#pragma unroll
      for (int c = 0; c < C_CLS; c++) rs[c] = rsn[c];
    }
    __syncthreads();
  }

#pragma unroll
  for (int c = 0; c < C_CLS; c++) wo[h * C_CLS + c] = x[c];
  float s = 0.f;
#pragma unroll
  for (int c = 0; c < C_CLS; c++) s += fabsf(x[c]);
  t7[0] = s;
#pragma unroll
  for (int c = 1; c < C_CLS; c++) t7[c] = 0.f;
  block_reduce7(t7, rsn, red);
  if (h == 0) *wo_flag = rsn[0];
}

// K4: if ||wo||_1 == 0 (data-driven common case): out already holds the exact
// result (zeros, pre-filled by k_preds) -> immediate exit, node costs only
// dispatch. Else: full out[i][c] = sum_h relu(feat_i . W[:,h]) * wo[h][c],
// grid-stride over points (overwrites every element of out).
__global__ void k_out(const float* __restrict__ feat, const float* __restrict__ w,
                      const float* __restrict__ wo, const float* __restrict__ wo_flag,
                      float* __restrict__ out, int N) {
  if (*wo_flag == 0.0f) return;  // out == zeros == exact result
  int stride = gridDim.x * blockDim.x;
  for (int i = blockIdx.x * blockDim.x + threadIdx.x; i < N; i += stride) {
    float f[D_DIM];
    const float4* fp = (const float4*)(feat + (size_t)i * D_DIM);
#pragma unroll
    for (int q = 0; q < D_DIM / 4; q++) {
      float4 v = fp[q];
      f[4 * q] = v.x; f[4 * q + 1] = v.y; f[4 * q + 2] = v.z; f[4 * q + 3] = v.w;
    }
    float acc[C_CLS];
#pragma unroll
    for (int c = 0; c < C_CLS; c++) acc[c] = 0.f;
    for (int hh = 0; hh < H_DIM; hh++) {
      float s = 0.f;
#pragma unroll 8
      for (int d = 0; d < D_DIM; d++) s += f[d] * w[(size_t)d * H_DIM + hh];
      s = fmaxf(s, 0.f);
      const float* wrow = wo + hh * C_CLS;
#pragma unroll
      for (int c = 0; c < C_CLS; c++) acc[c] += s * wrow[c];
    }
#pragma unroll
    for (int c = 0; c < C_CLS; c++) out[(size_t)i * C_CLS + c] = acc[c];
  }
}

extern "C" void kernel_launch(void* const* d_in, const int* in_sizes, int n_in,
                              void* d_out, int out_size, void* d_ws, size_t ws_size,
                              hipStream_t stream) {
  const float* feat   = (const float*)d_in[0];
  const float* proto  = (const float*)d_in[1];
  const float* w      = (const float*)d_in[2];
  const float* Q      = (const float*)d_in[3];
  const float* G      = (const float*)d_in[4];
  const float* coords = (const float*)d_in[5];
  const float* normz  = (const float*)d_in[6];
  const void*  nearv  = d_in[7];
  float* out = (float*)d_out;

  const int N = in_sizes[0] / D_DIM;  // 100000

  char* WS = (char*)d_ws;
  int*            flags   = (int*)(WS + 4096);
  float*          wo_flag = (float*)(WS + 4160);
  unsigned char*  preds   = (unsigned char*)(WS + 8192);
  int*            list    = (int*)(WS + 408192);
  float*          wo      = (float*)(WS + 836864);
  float*          Gn      = (float*)(WS + 865536);
  // total ws need: 5059840 bytes
  if (ws_size < 5059840) return;  // constant per session; visible failure if hit

  int nblk = (N + 255) / 256;  // 391 blocks: 1.5 blocks/CU, all CUs active
  hipLaunchKernelGGL(k_preds, dim3(nblk), dim3(256), 0, stream,
                     feat, proto, (const long long*)nearv, preds, flags, out, N);
  hipLaunchKernelGGL(k_mask, dim3(nblk), dim3(256), 0, stream,
                     preds, nearv, coords, normz, flags, list, N);
  hipLaunchKernelGGL(k_ridge, dim3(1), dim3(1024), 0, stream,
                     feat, w, Q, G, preds, flags, list, Gn, wo, wo_flag);
  hipLaunchKernelGGL(k_out, dim3(nblk), dim3(256), 0, stream,
                     feat, w, wo, wo_flag, out, N);
}